// Round 10
// baseline (2906.318 us; speedup 1.0000x reference)
//
#include <hip/hip_runtime.h>
#include <cstdint>
#include <cmath>

// Workspace layout (bytes):
//   h       : 0            .. 67108864   (8*512*64*64 f32)
//   boxes   : 67108864     .. 71827456   (8*36864*4 f32)
//   scores  : 71827456     .. 73007104   (8*36864 f32)
//   sel     : 73007104     .. 73199104   (8*6000 u32)
//   zeropad : 73199104     .. 73199360   (256B zeros)
//   wT      : 73199360     .. 82636544   (512*9*512 f32)
//
// CORRECTNESS ANCHOR (rounds 5-7 lesson): the conv MUST accumulate per-output
// in strict (ci asc, ky, kx) sequential-FMA fp32 order. MFMA tree-sums flip a
// near-tie in the NMS cascade (absmax 369 at ANY precision). v_pk_fma_f32
// packs across DIFFERENT accumulators -> per-acc chains bitwise unchanged.

#define AS1U(p) ((const __attribute__((address_space(1))) unsigned int*)(p))
#define AS3U(p) ((__attribute__((address_space(3))) unsigned int*)(p))

typedef float f32x2 __attribute__((ext_vector_type(2)));
typedef float f32x4 __attribute__((ext_vector_type(4)));

// ---------------- Stage A0: tiled transpose w[co][ci*9+k] -> wT[ci*9+k][co] ----------------
// 64x64 tiles via LDS: both global sides coalesced (old version: 2.4M
// uncoalesced reads = ~150MB of 64B sectors).
__global__ __launch_bounds__(256) void k_wtrans_t(
        const float* __restrict__ w, float* __restrict__ wT) {
    __shared__ float tile[64][65];
    const int cik0 = blockIdx.x * 64;     // 72 tiles
    const int co0 = blockIdx.y * 64;      // 8 tiles
    const int t = threadIdx.x;
    const int l = t & 63;                 // fast lane
    const int r = t >> 6;                 // 0..3
#pragma unroll
    for (int it = 0; it < 16; ++it) {
        const int co_l = r + 4 * it;
        tile[l][co_l] = w[(size_t)(co0 + co_l) * 4608 + cik0 + l];
    }
    __syncthreads();
#pragma unroll
    for (int it = 0; it < 16; ++it) {
        const int cik_l = r + 4 * it;
        wT[(size_t)(cik0 + cik_l) * 512 + co0 + l] = tile[cik_l][l];
    }
}

// ---------------- Stage A: 3x3 conv + bias + relu (fp32, packed-FMA, ci-chunk 16) ----------------
// Block: 256 thr = xq(8) x coq(8) x yy(4).  Per thread: 8co x 8x x 1y.
// acc2[c2][i] packs co-pair (2*c2, 2*c2+1): each component's fma chain is
// bitwise-identical to the round-3/4 scalar kernel (same order, fma rounding).
// ci-chunk 16 (was 8): halves barrier/vmcnt-drain count; ci order unchanged.
// LDS = 16*6*68*4 + 16*9*68*4 = 65280 B (<= 64KB static cap), 2 blocks/CU.
__global__ __launch_bounds__(256) void k_conv3x3_pk(
        const float* __restrict__ x, const float* __restrict__ wT,
        const float* __restrict__ bias, const float* __restrict__ zeropad,
        float* __restrict__ hout) {
    __shared__ __align__(16) float xs[16][6][68];
    __shared__ __align__(16) float wl[16][9][68];

    const int ytile = blockIdx.x;
    const int co0 = blockIdx.y * 64;
    const int b = blockIdx.z;
    const int t = threadIdx.x;
    const int xq = t & 7;
    const int coq = (t >> 3) & 7;
    const int yy = t >> 6;
    const int lane = t & 63;
    const int y0 = ytile * 4;

    if (t < 96) { int ci = t / 6, ry = t % 6; xs[ci][ry][0] = 0.f; xs[ci][ry][65] = 0.f; }

    f32x2 acc2[4][8];
#pragma unroll
    for (int c = 0; c < 4; ++c)
#pragma unroll
        for (int i = 0; i < 8; ++i) acc2[c][i] = (f32x2){0.f, 0.f};

    const int gy0 = y0 - 1;
    const float* xb = x + ((size_t)b * 512) * 4096;

    for (int ci0 = 0; ci0 < 512; ci0 += 16) {
        __syncthreads();
        // ---- stage x: 24 row loads per wave (ci = 4*yy + j/6) ----
#pragma unroll
        for (int j = 0; j < 24; ++j) {
            const int ci = 4 * yy + (j / 6);
            const int ry = j % 6;
            const int gy = gy0 + ry;
            const float* src = (gy >= 0 && gy < 64)
                ? xb + ((size_t)(ci0 + ci) * 64 + gy) * 64 + lane
                : zeropad + lane;
            __builtin_amdgcn_global_load_lds(AS1U(src), AS3U(&xs[ci][ry][1]), 4, 0, 0);
        }
        // ---- stage w: 36 row loads per wave from wT ----
#pragma unroll
        for (int c2 = 0; c2 < 4; ++c2) {
            const int cil = 4 * yy + c2;
#pragma unroll
            for (int k = 0; k < 9; ++k) {
                const float* src = wT + ((size_t)(ci0 + cil) * 9 + k) * 512 + co0 + lane;
                __builtin_amdgcn_global_load_lds(AS1U(src), AS3U(&wl[cil][k][0]), 4, 0, 0);
            }
        }
        __syncthreads();
        // ---- compute: strict (ci, ky, kx) sequential FMA per accumulator ----
#pragma unroll
        for (int ci = 0; ci < 16; ++ci) {
#pragma unroll
            for (int ky = 0; ky < 3; ++ky) {
                const float* xr = &xs[ci][yy + ky][xq * 8];
                const f32x4 a0 = *(const f32x4*)(xr);
                const f32x4 a1 = *(const f32x4*)(xr + 4);
                const f32x2 a2 = *(const f32x2*)(xr + 8);
                f32x2 xw2[10];
                xw2[0] = (f32x2){a0[0], a0[0]}; xw2[1] = (f32x2){a0[1], a0[1]};
                xw2[2] = (f32x2){a0[2], a0[2]}; xw2[3] = (f32x2){a0[3], a0[3]};
                xw2[4] = (f32x2){a1[0], a1[0]}; xw2[5] = (f32x2){a1[1], a1[1]};
                xw2[6] = (f32x2){a1[2], a1[2]}; xw2[7] = (f32x2){a1[3], a1[3]};
                xw2[8] = (f32x2){a2[0], a2[0]}; xw2[9] = (f32x2){a2[1], a2[1]};
#pragma unroll
                for (int kx = 0; kx < 3; ++kx) {
                    const f32x4 w0 = *(const f32x4*)&wl[ci][ky * 3 + kx][coq * 8];
                    const f32x4 w1 = *(const f32x4*)&wl[ci][ky * 3 + kx][coq * 8 + 4];
                    const f32x2 w00 = (f32x2){w0[0], w0[1]};
                    const f32x2 w01 = (f32x2){w0[2], w0[3]};
                    const f32x2 w10 = (f32x2){w1[0], w1[1]};
                    const f32x2 w11 = (f32x2){w1[2], w1[3]};
#pragma unroll
                    for (int i = 0; i < 8; ++i) {
                        const f32x2 xv2 = xw2[i + kx];
                        acc2[0][i] = __builtin_elementwise_fma(w00, xv2, acc2[0][i]);
                        acc2[1][i] = __builtin_elementwise_fma(w01, xv2, acc2[1][i]);
                        acc2[2][i] = __builtin_elementwise_fma(w10, xv2, acc2[2][i]);
                        acc2[3][i] = __builtin_elementwise_fma(w11, xv2, acc2[3][i]);
                    }
                }
            }
        }
    }
    const int y = y0 + yy;
#pragma unroll
    for (int c = 0; c < 8; ++c) {
        const int co = co0 + coq * 8 + c;
        const float bv = bias[co];
        float* op = hout + (((size_t)b * 512 + co) * 64 + y) * 64 + xq * 8;
        float4 o0, o1;
        o0.x = fmaxf(acc2[c >> 1][0][c & 1] + bv, 0.f);
        o0.y = fmaxf(acc2[c >> 1][1][c & 1] + bv, 0.f);
        o0.z = fmaxf(acc2[c >> 1][2][c & 1] + bv, 0.f);
        o0.w = fmaxf(acc2[c >> 1][3][c & 1] + bv, 0.f);
        o1.x = fmaxf(acc2[c >> 1][4][c & 1] + bv, 0.f);
        o1.y = fmaxf(acc2[c >> 1][5][c & 1] + bv, 0.f);
        o1.z = fmaxf(acc2[c >> 1][6][c & 1] + bv, 0.f);
        o1.w = fmaxf(acc2[c >> 1][7][c & 1] + bv, 0.f);
        *(float4*)(op) = o0;
        *(float4*)(op + 4) = o1;
    }
}

// ---------------- Stage A (fallback, same arithmetic order): w from global ----------------
__global__ __launch_bounds__(256) void k_conv3x3(
        const float* __restrict__ x, const float* __restrict__ w,
        const float* __restrict__ bias, const float* __restrict__ zeropad,
        float* __restrict__ hout) {
    __shared__ __align__(16) float xs[8][6][68];
    __shared__ __align__(16) float wl[8][9][68];
    const int ytile = blockIdx.x;
    const int co0 = blockIdx.y * 64;
    const int b = blockIdx.z;
    const int t = threadIdx.x;
    const int xq = t & 7;
    const int coq = (t >> 3) & 7;
    const int yy = t >> 6;
    const int lane = t & 63;
    const int y0 = ytile * 4;
    if (t < 48) { int ci = t / 6, ry = t % 6; xs[ci][ry][0] = 0.f; xs[ci][ry][65] = 0.f; }
    float acc[8][8];
#pragma unroll
    for (int c = 0; c < 8; ++c)
#pragma unroll
        for (int i = 0; i < 8; ++i) acc[c][i] = 0.f;
    const int co_s = t >> 2, qs = t & 3;
    const float* wsrc = w + (size_t)(co0 + co_s) * 4608 + qs * 18;
    float* wrow = &wl[0][0][0] + (size_t)(2 * qs) * 9 * 68 + co_s;
    const int gy0 = y0 - 1;
    const float* xb = x + ((size_t)b * 512) * 4096;
    for (int ci0 = 0; ci0 < 512; ci0 += 8) {
        __syncthreads();
#pragma unroll
        for (int j = 0; j < 12; ++j) {
            const int ci = 2 * yy + (j >= 6 ? 1 : 0);
            const int ry = (j >= 6) ? (j - 6) : j;
            const int gy = gy0 + ry;
            const float* src = (gy >= 0 && gy < 64)
                ? xb + ((size_t)(ci0 + ci) * 64 + gy) * 64 + lane
                : zeropad + lane;
            __builtin_amdgcn_global_load_lds(AS1U(src), AS3U(&xs[ci][ry][1]), 4, 0, 0);
        }
        {
            const float2* wp2 = (const float2*)(wsrc + (size_t)ci0 * 9);
#pragma unroll
            for (int j2 = 0; j2 < 9; ++j2) {
                float2 f = wp2[j2];
                const int i0 = 2 * j2, i1 = 2 * j2 + 1;
                wrow[(i0 < 9 ? 0 : 9 * 68) + (i0 < 9 ? i0 : i0 - 9) * 68] = f.x;
                wrow[(i1 < 9 ? 0 : 9 * 68) + (i1 < 9 ? i1 : i1 - 9) * 68] = f.y;
            }
        }
        __syncthreads();
#pragma unroll
        for (int ci = 0; ci < 8; ++ci) {
#pragma unroll
            for (int ky = 0; ky < 3; ++ky) {
                const float* xr = &xs[ci][yy + ky][xq * 8];
                const float4 a0 = *(const float4*)(xr);
                const float4 a1 = *(const float4*)(xr + 4);
                const float2 a2 = *(const float2*)(xr + 8);
                float xw[10];
                xw[0] = a0.x; xw[1] = a0.y; xw[2] = a0.z; xw[3] = a0.w;
                xw[4] = a1.x; xw[5] = a1.y; xw[6] = a1.z; xw[7] = a1.w;
                xw[8] = a2.x; xw[9] = a2.y;
#pragma unroll
                for (int kx = 0; kx < 3; ++kx) {
                    const float4 w0 = *(const float4*)&wl[ci][ky * 3 + kx][coq * 8];
                    const float4 w1 = *(const float4*)&wl[ci][ky * 3 + kx][coq * 8 + 4];
#pragma unroll
                    for (int i = 0; i < 8; ++i) {
                        const float xv = xw[i + kx];
                        acc[0][i] += w0.x * xv; acc[1][i] += w0.y * xv;
                        acc[2][i] += w0.z * xv; acc[3][i] += w0.w * xv;
                        acc[4][i] += w1.x * xv; acc[5][i] += w1.y * xv;
                        acc[6][i] += w1.z * xv; acc[7][i] += w1.w * xv;
                    }
                }
            }
        }
    }
    const int y = y0 + yy;
#pragma unroll
    for (int c = 0; c < 8; ++c) {
        const int co = co0 + coq * 8 + c;
        const float bv = bias[co];
        float* op = hout + (((size_t)b * 512 + co) * 64 + y) * 64 + xq * 8;
        float4 o0, o1;
        o0.x = fmaxf(acc[c][0] + bv, 0.f); o0.y = fmaxf(acc[c][1] + bv, 0.f);
        o0.z = fmaxf(acc[c][2] + bv, 0.f); o0.w = fmaxf(acc[c][3] + bv, 0.f);
        o1.x = fmaxf(acc[c][4] + bv, 0.f); o1.y = fmaxf(acc[c][5] + bv, 0.f);
        o1.z = fmaxf(acc[c][6] + bv, 0.f); o1.w = fmaxf(acc[c][7] + bv, 0.f);
        *(float4*)(op) = o0;
        *(float4*)(op + 4) = o1;
    }
}

// ---------------- Stage B: 1x1 heads + sigmoid + decode ----------------
// 256 blocks x 128 thr (one block per CU; round-9 ran on only 128 CUs).
// Weights in TRANSPOSED LDS [cc][60]: per-ci reads are 13 b128 + 1 b64
// (vs 54 scalar b32 broadcasts), consumed as 27 pk_fma pairs.
// Per-accumulator cc-ascending fma chain unchanged -> bitwise identical.
__global__ __launch_bounds__(128) void k_head(
        const float* __restrict__ h,
        const float* __restrict__ cls_w, const float* __restrict__ cls_b,
        const float* __restrict__ loc_w, const float* __restrict__ loc_b,
        const int* __restrict__ img_h_p, const int* __restrict__ img_w_p,
        float* __restrict__ out_cls, float* __restrict__ out_loc,
        float* __restrict__ boxes, float* __restrict__ scores) {
    __shared__ __align__(16) float wAll[128][60];   // [cc][o], o: 0..17 cls, 18..53 loc
    const int t = threadIdx.x;
    const int tg = blockIdx.x * 128 + t;
    const int b = tg >> 12;
    const int pos = tg & 4095;
    const int y = pos >> 6, xc = pos & 63;
    f32x2 acc2[27];
#pragma unroll
    for (int p = 0; p < 27; ++p) acc2[p] = (f32x2){0.f, 0.f};
    const float* hp = h + (size_t)b * 2097152 + pos;
    for (int c4 = 0; c4 < 4; ++c4) {
        const int ci0 = c4 * 128;
        __syncthreads();
#pragma unroll
        for (int j = 0; j < 54; ++j) {
            wAll[t][j] = (j < 18) ? cls_w[j * 512 + ci0 + t]
                                  : loc_w[(j - 18) * 512 + ci0 + t];
        }
        __syncthreads();
#pragma unroll 4
        for (int cc = 0; cc < 128; ++cc) {
            const float hv = hp[(size_t)(ci0 + cc) * 4096];
            const f32x2 hv2 = (f32x2){hv, hv};
            const float* wr = &wAll[cc][0];
#pragma unroll
            for (int q = 0; q < 13; ++q) {
                const f32x4 w4 = *(const f32x4*)(wr + 4 * q);
                acc2[2 * q]     = __builtin_elementwise_fma((f32x2){w4[0], w4[1]}, hv2, acc2[2 * q]);
                acc2[2 * q + 1] = __builtin_elementwise_fma((f32x2){w4[2], w4[3]}, hv2, acc2[2 * q + 1]);
            }
            const f32x2 wtl = *(const f32x2*)(wr + 52);
            acc2[26] = __builtin_elementwise_fma(wtl, hv2, acc2[26]);
        }
    }
    float accC[18], accL[36];
#pragma unroll
    for (int o = 0; o < 18; ++o) accC[o] = acc2[o >> 1][o & 1];
#pragma unroll
    for (int l = 0; l < 36; ++l) accL[l] = acc2[9 + (l >> 1)][l & 1];
    const float fh = (float)(*img_h_p);
    const float fw = (float)(*img_w_p);
    {
        const size_t obase = (size_t)b * 73728 + (size_t)pos * 18;
#pragma unroll
        for (int o = 0; o < 18; ++o) {
            accC[o] += cls_b[o];
            out_cls[obase + o] = 1.f / (1.f + expf(-accC[o]));
        }
    }
    {
        const size_t lbase = (size_t)b * 147456 + (size_t)pos * 36;
#pragma unroll
        for (int o = 0; o < 36; ++o) {
            accL[o] += loc_b[o];
            out_loc[lbase + o] = accL[o];
        }
    }
    const float sy = (float)(y * 16), sx = (float)(xc * 16);
    const double RR[3] = {0.5, 1.0, 2.0};
    const double SS[3] = {8.0, 16.0, 32.0};
#pragma unroll
    for (int a = 0; a < 9; ++a) {
        const double r = RR[a / 3], s = SS[a % 3];
        const double hd = 16.0 * s * sqrt(r);
        const double wd = 16.0 * s * sqrt(1.0 / r);
        const float ab0 = (float)(-hd / 2.0), ab1 = (float)(-wd / 2.0);
        const float ab2 = (float)(hd / 2.0), ab3 = (float)(wd / 2.0);
        const float a0 = ab0 + sy, a1 = ab1 + sx, a2 = ab2 + sy, a3 = ab3 + sx;
        float hh = a2 - a0, ww = a3 - a1;
        float cy = a0 + 0.5f * hh, cx = a1 + 0.5f * ww;
        const float dy = accL[a * 4 + 0], dx = accL[a * 4 + 1];
        const float dh = accL[a * 4 + 2], dw = accL[a * 4 + 3];
        cy = cy + dy * hh;
        cx = cx + dx * ww;
        hh = hh * expf(dh);
        ww = ww * expf(dw);
        float y1 = cy - 0.5f * hh, x1 = cx - 0.5f * ww;
        float y2 = cy + 0.5f * hh, x2 = cx + 0.5f * ww;
        y1 = fminf(fmaxf(y1, 0.f), fh); x1 = fminf(fmaxf(x1, 0.f), fw);
        y2 = fminf(fmaxf(y2, 0.f), fh); x2 = fminf(fmaxf(x2, 0.f), fw);
        const bool valid = ((y2 - y1) >= 16.f) && ((x2 - x1) >= 16.f);
        const float sc = 1.f / (1.f + expf(-accC[a * 2 + 1]));
        const int n = pos * 9 + a;
        float* bp = boxes + ((size_t)b * 36864 + n) * 4;
        bp[0] = y1; bp[1] = x1; bp[2] = y2; bp[3] = x2;
        scores[(size_t)b * 36864 + n] = valid ? sc : -INFINITY;
    }
}

// ---------------- Stage C: exact top-6000 select (radix, per-wave LDS hist, f4 loads) ----------------
__device__ __forceinline__ unsigned fmap(float f) {
    unsigned bits = __float_as_uint(f);
    return ((int)bits < 0) ? ~bits : (bits | 0x80000000u);
}

__global__ __launch_bounds__(1024) void k_select(
        const float* __restrict__ scores, unsigned* __restrict__ sel) {
    __shared__ unsigned h2[16][256];
    __shared__ unsigned hist[256];
    __shared__ unsigned tieL[1024];
    __shared__ unsigned sh_pref, sh_k, sh_cg, sh_ct;
    const int b = blockIdx.x;
    const int t = threadIdx.x;
    const int lane = t & 63;
    const int wid = t >> 6;
    const unsigned long long lmlt = (1ull << lane) - 1ull;
    const float* sp = scores + (size_t)b * 36864;
    unsigned pref = 0;
    unsigned k = 6000;
    for (int p = 3; p >= 0; --p) {
        for (int z = t; z < 4096; z += 1024) ((unsigned*)h2)[z] = 0;
        __syncthreads();
        const int sh = p * 8;
        for (int i4 = t * 4; i4 < 36864; i4 += 4096) {
            const float4 v = *(const float4*)(sp + i4);
            const float vv[4] = {v.x, v.y, v.z, v.w};
#pragma unroll
            for (int e = 0; e < 4; ++e) {
                unsigned u = fmap(vv[e]);
                bool match = (p == 3) || ((u >> (sh + 8)) == (pref >> (sh + 8)));
                if (match) atomicAdd(&h2[wid][(u >> sh) & 255u], 1u);
            }
        }
        __syncthreads();
        if (t < 256) {
            unsigned s = 0;
#pragma unroll
            for (int j = 0; j < 16; ++j) s += h2[j][t];
            hist[t] = s;
        }
        __syncthreads();
        if (t == 0) {
            unsigned c = 0;
            int bsel = 0;
            for (int bin = 255; bin >= 0; --bin) {
                unsigned c2 = c + hist[bin];
                if (c2 >= k) { bsel = bin; k = k - c; break; }
                c = c2;
            }
            pref |= ((unsigned)bsel) << sh;
            sh_pref = pref; sh_k = k;
        }
        __syncthreads();
        pref = sh_pref; k = sh_k;
        __syncthreads();
    }
    if (t == 0) { sh_cg = 0; sh_ct = 0; }
    __syncthreads();
    const unsigned uthr = pref;
    for (int i4 = t * 4; i4 < 36864; i4 += 4096) {
        const float4 v = *(const float4*)(sp + i4);
        const float vv[4] = {v.x, v.y, v.z, v.w};
#pragma unroll
        for (int e = 0; e < 4; ++e) {
            const int i = i4 + e;
            unsigned u = fmap(vv[e]);
            const bool g = (u > uthr);
            const bool eq = (u == uthr);
            unsigned long long bg = __ballot(g);
            if (bg) {
                int lead = __ffsll((unsigned long long)bg) - 1;
                unsigned basev = 0;
                if (lane == lead) basev = atomicAdd(&sh_cg, (unsigned)__popcll(bg));
                basev = __shfl(basev, lead, 64);
                if (g) sel[(size_t)b * 6000 + basev + (unsigned)__popcll(bg & lmlt)] = (unsigned)i;
            }
            unsigned long long be = __ballot(eq);
            if (be) {
                int lead = __ffsll((unsigned long long)be) - 1;
                unsigned baset = 0;
                if (lane == lead) baset = atomicAdd(&sh_ct, (unsigned)__popcll(be));
                baset = __shfl(baset, lead, 64);
                if (eq) {
                    unsigned tp = baset + (unsigned)__popcll(be & lmlt);
                    if (tp < 1024) tieL[tp] = (unsigned)i;
                }
            }
        }
    }
    __syncthreads();
    const unsigned G = sh_cg;
    const unsigned T = sh_ct;
    const unsigned need = k;
    const unsigned Tc = T < 1024u ? T : 1024u;
    if ((unsigned)t >= Tc) tieL[t] = 0xFFFFFFFFu;
    __syncthreads();
    if (need > 0) {
        if (T > 1) {
            for (int kk = 2; kk <= 1024; kk <<= 1) {
                for (int j = kk >> 1; j > 0; j >>= 1) {
                    int ixj = t ^ j;
                    if (ixj > t) {
                        unsigned va = tieL[t], vb = tieL[ixj];
                        bool up = ((t & kk) == 0);
                        if (up ? (va > vb) : (va < vb)) { tieL[t] = vb; tieL[ixj] = va; }
                    }
                    __syncthreads();
                }
            }
        }
        if ((unsigned)t < need) sel[(size_t)b * 6000 + G + t] = tieL[t];
    }
}

// ---------------- Stage D: sequential 300-pick NMS (LDS winner broadcast) ----------------
__global__ __launch_bounds__(1024) void k_nms(
        const float* __restrict__ boxes, const float* __restrict__ scores,
        const unsigned* __restrict__ sel,
        float* __restrict__ rois, float* __restrict__ roi_idx) {
    __shared__ unsigned long long warr[2][16];
    __shared__ float wbox[2][16][4];
    const int b = blockIdx.x;
    const int t = threadIdx.x;
    const unsigned UNEG = 0x007FFFFFu;
    float bx[6][4];
    unsigned long long key[6];
#pragma unroll
    for (int j = 0; j < 6; ++j) {
        int s = t + j * 1024;
        if (s < 6000) {
            unsigned idx = sel[(size_t)b * 6000 + s];
            const float* bp = boxes + ((size_t)b * 36864 + idx) * 4;
            bx[j][0] = bp[0]; bx[j][1] = bp[1]; bx[j][2] = bp[2]; bx[j][3] = bp[3];
            unsigned u = fmap(scores[(size_t)b * 36864 + idx]);
            key[j] = ((unsigned long long)u << 32) | (unsigned)(~idx);
        } else {
            key[j] = 0ull;
            bx[j][0] = bx[j][1] = bx[j][2] = bx[j][3] = 0.f;
        }
    }
    const int lane = t & 63;
    const int wid = t >> 6;
    float* orow = rois + (size_t)b * 300 * 4;
    for (int k = 0; k < 300; ++k) {
        const int pb = k & 1;
        unsigned long long m = key[0];
        float b0 = bx[0][0], b1 = bx[0][1], b2 = bx[0][2], b3 = bx[0][3];
#pragma unroll
        for (int j = 1; j < 6; ++j) {
            if (key[j] > m) { m = key[j]; b0 = bx[j][0]; b1 = bx[j][1]; b2 = bx[j][2]; b3 = bx[j][3]; }
        }
        const unsigned long long lm = m;
#pragma unroll
        for (int d = 32; d > 0; d >>= 1) {
            unsigned long long o = __shfl_xor(m, d, 64);
            if (o > m) m = o;
        }
        unsigned long long own = __ballot(lm == m);
        if (lane == __ffsll(own) - 1) {
            warr[pb][wid] = m;
            wbox[pb][wid][0] = b0; wbox[pb][wid][1] = b1;
            wbox[pb][wid][2] = b2; wbox[pb][wid][3] = b3;
        }
        __syncthreads();
        unsigned long long wk = warr[pb][0];
        int wm = 0;
#pragma unroll
        for (int i = 1; i < 16; ++i) {
            unsigned long long v = warr[pb][i];
            if (v > wk) { wk = v; wm = i; }
        }
        const unsigned uhi = (unsigned)(wk >> 32);
        if (uhi > UNEG) {
            const float py1 = wbox[pb][wm][0], px1 = wbox[pb][wm][1];
            const float py2 = wbox[pb][wm][2], px2 = wbox[pb][wm][3];
            const float parea = (py2 - py1) * (px2 - px1);
            if (t == 0) {
                orow[k * 4 + 0] = py1; orow[k * 4 + 1] = px1;
                orow[k * 4 + 2] = py2; orow[k * 4 + 3] = px2;
                roi_idx[b * 300 + k] = (float)b;
            }
#pragma unroll
            for (int j = 0; j < 6; ++j) {
                if ((unsigned)(key[j] >> 32) > UNEG) {
                    float yy1 = fmaxf(bx[j][0], py1);
                    float xx1 = fmaxf(bx[j][1], px1);
                    float yy2 = fminf(bx[j][2], py2);
                    float xx2 = fminf(bx[j][3], px2);
                    float inter = fmaxf(yy2 - yy1, 0.f) * fmaxf(xx2 - xx1, 0.f);
                    float area = (bx[j][2] - bx[j][0]) * (bx[j][3] - bx[j][1]);
                    float iou = inter / (area + parea - inter + 1e-9f);
                    if (iou > 0.7f)
                        key[j] = ((unsigned long long)UNEG << 32) | (key[j] & 0xFFFFFFFFull);
                }
            }
        } else {
            if (t == 0) {
                orow[k * 4 + 0] = 0.f; orow[k * 4 + 1] = 0.f;
                orow[k * 4 + 2] = 0.f; orow[k * 4 + 3] = 0.f;
                roi_idx[b * 300 + k] = (float)b;
            }
        }
    }
}

extern "C" void kernel_launch(void* const* d_in, const int* in_sizes, int n_in,
                              void* d_out, int out_size, void* d_ws, size_t ws_size,
                              hipStream_t stream) {
    (void)in_sizes; (void)n_in; (void)out_size;
    const float* x      = (const float*)d_in[0];
    const float* conv_w = (const float*)d_in[1];
    const float* conv_b = (const float*)d_in[2];
    const float* loc_w  = (const float*)d_in[3];
    const float* loc_b  = (const float*)d_in[4];
    const float* cls_w  = (const float*)d_in[5];
    const float* cls_b  = (const float*)d_in[6];
    const int* img_h    = (const int*)d_in[7];
    const int* img_w    = (const int*)d_in[8];

    char* ws = (char*)d_ws;
    float*    h      = (float*)(ws + 0);
    float*    boxes  = (float*)(ws + 67108864);
    float*    scores = (float*)(ws + 71827456);
    unsigned* sel    = (unsigned*)(ws + 73007104);
    float*    zp     = (float*)(ws + 73199104);
    float*    wT     = (float*)(ws + 73199360);

    float* out      = (float*)d_out;
    float* out_cls  = out;             // 589824
    float* out_loc  = out + 589824;    // 1179648
    float* rois     = out + 1769472;   // 9600
    float* ridx     = out + 1779072;   // 2400

    const bool big_ws = (ws_size >= 82636544ull);

    hipMemsetAsync(zp, 0, 256, stream);
    if (big_ws) {
        k_wtrans_t<<<dim3(72, 8), 256, 0, stream>>>(conv_w, wT);
        k_conv3x3_pk<<<dim3(16, 8, 8), 256, 0, stream>>>(x, wT, conv_b, zp, h);
    } else {
        k_conv3x3<<<dim3(16, 8, 8), 256, 0, stream>>>(x, conv_w, conv_b, zp, h);
    }
    k_head<<<dim3(256), 128, 0, stream>>>(h, cls_w, cls_b, loc_w, loc_b,
                                          img_h, img_w, out_cls, out_loc, boxes, scores);
    k_select<<<dim3(8), 1024, 0, stream>>>(scores, sel);
    k_nms<<<dim3(8), 1024, 0, stream>>>(boxes, scores, sel, rois, ridx);
}

// Round 11
// 2887.882 us; speedup vs baseline: 1.0064x; 1.0064x over previous
//
#include <hip/hip_runtime.h>
#include <cstdint>
#include <cmath>

// Workspace layout (bytes):
//   h       : 0            .. 67108864   (8*512*64*64 f32)
//   boxes   : 67108864     .. 71827456   (8*36864*4 f32)
//   scores  : 71827456     .. 73007104   (8*36864 f32)
//   (free)  : 73007104     .. 73199104   (old sel slot, now in LDS)
//   zeropad : 73199104     .. 73199360   (256B zeros)
//   wT      : 73199360     .. 82636544   (512*9*512 f32)
//
// CORRECTNESS ANCHOR (rounds 5-7 lesson): the conv MUST accumulate per-output
// in strict (ci asc, ky, kx) sequential-FMA fp32 order. MFMA tree-sums flip a
// near-tie in the NMS cascade (absmax 369 at ANY precision). v_pk_fma_f32
// packs across DIFFERENT accumulators -> per-acc chains bitwise unchanged.
// Conv is at ~93% of the sustained pk-FMA roofline (192 TF vs ~206 TF m07-scaled).

#define AS1U(p) ((const __attribute__((address_space(1))) unsigned int*)(p))
#define AS3U(p) ((__attribute__((address_space(3))) unsigned int*)(p))

typedef float f32x2 __attribute__((ext_vector_type(2)));
typedef float f32x4 __attribute__((ext_vector_type(4)));

// ---------------- Stage A0: tiled transpose w[co][ci*9+k] -> wT[ci*9+k][co] ----------------
__global__ __launch_bounds__(256) void k_wtrans_t(
        const float* __restrict__ w, float* __restrict__ wT) {
    __shared__ float tile[64][65];
    const int cik0 = blockIdx.x * 64;     // 72 tiles
    const int co0 = blockIdx.y * 64;      // 8 tiles
    const int t = threadIdx.x;
    const int l = t & 63;
    const int r = t >> 6;
#pragma unroll
    for (int it = 0; it < 16; ++it) {
        const int co_l = r + 4 * it;
        tile[l][co_l] = w[(size_t)(co0 + co_l) * 4608 + cik0 + l];
    }
    __syncthreads();
#pragma unroll
    for (int it = 0; it < 16; ++it) {
        const int cik_l = r + 4 * it;
        wT[(size_t)(cik0 + cik_l) * 512 + co0 + l] = tile[cik_l][l];
    }
}

// ---------------- Stage A: 3x3 conv + bias + relu (fp32, packed-FMA, ci-chunk 8) ----------------
// EXACT round-9 structure (proven 1610us, absmax 0.25). Block: 256 thr =
// xq(8) x coq(8) x yy(4). Per thread: 8co x 8x x 1y. LDS 32.6KB.
__global__ __launch_bounds__(256) void k_conv3x3_pk(
        const float* __restrict__ x, const float* __restrict__ wT,
        const float* __restrict__ bias, const float* __restrict__ zeropad,
        float* __restrict__ hout) {
    __shared__ __align__(16) float xs[8][6][68];
    __shared__ __align__(16) float wl[8][9][68];

    const int ytile = blockIdx.x;
    const int co0 = blockIdx.y * 64;
    const int b = blockIdx.z;
    const int t = threadIdx.x;
    const int xq = t & 7;
    const int coq = (t >> 3) & 7;
    const int yy = t >> 6;
    const int lane = t & 63;
    const int y0 = ytile * 4;

    if (t < 48) { int ci = t / 6, ry = t % 6; xs[ci][ry][0] = 0.f; xs[ci][ry][65] = 0.f; }

    f32x2 acc2[4][8];
#pragma unroll
    for (int c = 0; c < 4; ++c)
#pragma unroll
        for (int i = 0; i < 8; ++i) acc2[c][i] = (f32x2){0.f, 0.f};

    const int gy0 = y0 - 1;
    const float* xb = x + ((size_t)b * 512) * 4096;

    for (int ci0 = 0; ci0 < 512; ci0 += 8) {
        __syncthreads();
        // ---- stage x: 12 row loads per wave ----
#pragma unroll
        for (int j = 0; j < 12; ++j) {
            const int ci = 2 * yy + (j >= 6 ? 1 : 0);
            const int ry = (j >= 6) ? (j - 6) : j;
            const int gy = gy0 + ry;
            const float* src = (gy >= 0 && gy < 64)
                ? xb + ((size_t)(ci0 + ci) * 64 + gy) * 64 + lane
                : zeropad + lane;
            __builtin_amdgcn_global_load_lds(AS1U(src), AS3U(&xs[ci][ry][1]), 4, 0, 0);
        }
        // ---- stage w: 18 row loads per wave from wT ----
#pragma unroll
        for (int c2 = 0; c2 < 2; ++c2) {
            const int cil = 2 * yy + c2;
#pragma unroll
            for (int k = 0; k < 9; ++k) {
                const float* src = wT + ((size_t)(ci0 + cil) * 9 + k) * 512 + co0 + lane;
                __builtin_amdgcn_global_load_lds(AS1U(src), AS3U(&wl[cil][k][0]), 4, 0, 0);
            }
        }
        __syncthreads();
        // ---- compute: strict (ci, ky, kx) sequential FMA per accumulator ----
#pragma unroll
        for (int ci = 0; ci < 8; ++ci) {
#pragma unroll
            for (int ky = 0; ky < 3; ++ky) {
                const float* xr = &xs[ci][yy + ky][xq * 8];
                const f32x4 a0 = *(const f32x4*)(xr);
                const f32x4 a1 = *(const f32x4*)(xr + 4);
                const f32x2 a2 = *(const f32x2*)(xr + 8);
                f32x2 xw2[10];
                xw2[0] = (f32x2){a0[0], a0[0]}; xw2[1] = (f32x2){a0[1], a0[1]};
                xw2[2] = (f32x2){a0[2], a0[2]}; xw2[3] = (f32x2){a0[3], a0[3]};
                xw2[4] = (f32x2){a1[0], a1[0]}; xw2[5] = (f32x2){a1[1], a1[1]};
                xw2[6] = (f32x2){a1[2], a1[2]}; xw2[7] = (f32x2){a1[3], a1[3]};
                xw2[8] = (f32x2){a2[0], a2[0]}; xw2[9] = (f32x2){a2[1], a2[1]};
#pragma unroll
                for (int kx = 0; kx < 3; ++kx) {
                    const f32x4 w0 = *(const f32x4*)&wl[ci][ky * 3 + kx][coq * 8];
                    const f32x4 w1 = *(const f32x4*)&wl[ci][ky * 3 + kx][coq * 8 + 4];
                    const f32x2 w00 = (f32x2){w0[0], w0[1]};
                    const f32x2 w01 = (f32x2){w0[2], w0[3]};
                    const f32x2 w10 = (f32x2){w1[0], w1[1]};
                    const f32x2 w11 = (f32x2){w1[2], w1[3]};
#pragma unroll
                    for (int i = 0; i < 8; ++i) {
                        const f32x2 xv2 = xw2[i + kx];
                        acc2[0][i] = __builtin_elementwise_fma(w00, xv2, acc2[0][i]);
                        acc2[1][i] = __builtin_elementwise_fma(w01, xv2, acc2[1][i]);
                        acc2[2][i] = __builtin_elementwise_fma(w10, xv2, acc2[2][i]);
                        acc2[3][i] = __builtin_elementwise_fma(w11, xv2, acc2[3][i]);
                    }
                }
            }
        }
    }
    const int y = y0 + yy;
#pragma unroll
    for (int c = 0; c < 8; ++c) {
        const int co = co0 + coq * 8 + c;
        const float bv = bias[co];
        float* op = hout + (((size_t)b * 512 + co) * 64 + y) * 64 + xq * 8;
        float4 o0, o1;
        o0.x = fmaxf(acc2[c >> 1][0][c & 1] + bv, 0.f);
        o0.y = fmaxf(acc2[c >> 1][1][c & 1] + bv, 0.f);
        o0.z = fmaxf(acc2[c >> 1][2][c & 1] + bv, 0.f);
        o0.w = fmaxf(acc2[c >> 1][3][c & 1] + bv, 0.f);
        o1.x = fmaxf(acc2[c >> 1][4][c & 1] + bv, 0.f);
        o1.y = fmaxf(acc2[c >> 1][5][c & 1] + bv, 0.f);
        o1.z = fmaxf(acc2[c >> 1][6][c & 1] + bv, 0.f);
        o1.w = fmaxf(acc2[c >> 1][7][c & 1] + bv, 0.f);
        *(float4*)(op) = o0;
        *(float4*)(op + 4) = o1;
    }
}

// ---------------- Stage A (fallback, same arithmetic order): w from global ----------------
__global__ __launch_bounds__(256) void k_conv3x3(
        const float* __restrict__ x, const float* __restrict__ w,
        const float* __restrict__ bias, const float* __restrict__ zeropad,
        float* __restrict__ hout) {
    __shared__ __align__(16) float xs[8][6][68];
    __shared__ __align__(16) float wl[8][9][68];
    const int ytile = blockIdx.x;
    const int co0 = blockIdx.y * 64;
    const int b = blockIdx.z;
    const int t = threadIdx.x;
    const int xq = t & 7;
    const int coq = (t >> 3) & 7;
    const int yy = t >> 6;
    const int lane = t & 63;
    const int y0 = ytile * 4;
    if (t < 48) { int ci = t / 6, ry = t % 6; xs[ci][ry][0] = 0.f; xs[ci][ry][65] = 0.f; }
    float acc[8][8];
#pragma unroll
    for (int c = 0; c < 8; ++c)
#pragma unroll
        for (int i = 0; i < 8; ++i) acc[c][i] = 0.f;
    const int co_s = t >> 2, qs = t & 3;
    const float* wsrc = w + (size_t)(co0 + co_s) * 4608 + qs * 18;
    float* wrow = &wl[0][0][0] + (size_t)(2 * qs) * 9 * 68 + co_s;
    const int gy0 = y0 - 1;
    const float* xb = x + ((size_t)b * 512) * 4096;
    for (int ci0 = 0; ci0 < 512; ci0 += 8) {
        __syncthreads();
#pragma unroll
        for (int j = 0; j < 12; ++j) {
            const int ci = 2 * yy + (j >= 6 ? 1 : 0);
            const int ry = (j >= 6) ? (j - 6) : j;
            const int gy = gy0 + ry;
            const float* src = (gy >= 0 && gy < 64)
                ? xb + ((size_t)(ci0 + ci) * 64 + gy) * 64 + lane
                : zeropad + lane;
            __builtin_amdgcn_global_load_lds(AS1U(src), AS3U(&xs[ci][ry][1]), 4, 0, 0);
        }
        {
            const float2* wp2 = (const float2*)(wsrc + (size_t)ci0 * 9);
#pragma unroll
            for (int j2 = 0; j2 < 9; ++j2) {
                float2 f = wp2[j2];
                const int i0 = 2 * j2, i1 = 2 * j2 + 1;
                wrow[(i0 < 9 ? 0 : 9 * 68) + (i0 < 9 ? i0 : i0 - 9) * 68] = f.x;
                wrow[(i1 < 9 ? 0 : 9 * 68) + (i1 < 9 ? i1 : i1 - 9) * 68] = f.y;
            }
        }
        __syncthreads();
#pragma unroll
        for (int ci = 0; ci < 8; ++ci) {
#pragma unroll
            for (int ky = 0; ky < 3; ++ky) {
                const float* xr = &xs[ci][yy + ky][xq * 8];
                const float4 a0 = *(const float4*)(xr);
                const float4 a1 = *(const float4*)(xr + 4);
                const float2 a2 = *(const float2*)(xr + 8);
                float xw[10];
                xw[0] = a0.x; xw[1] = a0.y; xw[2] = a0.z; xw[3] = a0.w;
                xw[4] = a1.x; xw[5] = a1.y; xw[6] = a1.z; xw[7] = a1.w;
                xw[8] = a2.x; xw[9] = a2.y;
#pragma unroll
                for (int kx = 0; kx < 3; ++kx) {
                    const float4 w0 = *(const float4*)&wl[ci][ky * 3 + kx][coq * 8];
                    const float4 w1 = *(const float4*)&wl[ci][ky * 3 + kx][coq * 8 + 4];
#pragma unroll
                    for (int i = 0; i < 8; ++i) {
                        const float xv = xw[i + kx];
                        acc[0][i] += w0.x * xv; acc[1][i] += w0.y * xv;
                        acc[2][i] += w0.z * xv; acc[3][i] += w0.w * xv;
                        acc[4][i] += w1.x * xv; acc[5][i] += w1.y * xv;
                        acc[6][i] += w1.z * xv; acc[7][i] += w1.w * xv;
                    }
                }
            }
        }
    }
    const int y = y0 + yy;
#pragma unroll
    for (int c = 0; c < 8; ++c) {
        const int co = co0 + coq * 8 + c;
        const float bv = bias[co];
        float* op = hout + (((size_t)b * 512 + co) * 64 + y) * 64 + xq * 8;
        float4 o0, o1;
        o0.x = fmaxf(acc[c][0] + bv, 0.f); o0.y = fmaxf(acc[c][1] + bv, 0.f);
        o0.z = fmaxf(acc[c][2] + bv, 0.f); o0.w = fmaxf(acc[c][3] + bv, 0.f);
        o1.x = fmaxf(acc[c][4] + bv, 0.f); o1.y = fmaxf(acc[c][5] + bv, 0.f);
        o1.z = fmaxf(acc[c][6] + bv, 0.f); o1.w = fmaxf(acc[c][7] + bv, 0.f);
        *(float4*)(op) = o0;
        *(float4*)(op + 4) = o1;
    }
}

// ---------------- Stage B: 1x1 heads + sigmoid + decode (round-10 version) ----------------
__global__ __launch_bounds__(128) void k_head(
        const float* __restrict__ h,
        const float* __restrict__ cls_w, const float* __restrict__ cls_b,
        const float* __restrict__ loc_w, const float* __restrict__ loc_b,
        const int* __restrict__ img_h_p, const int* __restrict__ img_w_p,
        float* __restrict__ out_cls, float* __restrict__ out_loc,
        float* __restrict__ boxes, float* __restrict__ scores) {
    __shared__ __align__(16) float wAll[128][60];
    const int t = threadIdx.x;
    const int tg = blockIdx.x * 128 + t;
    const int b = tg >> 12;
    const int pos = tg & 4095;
    const int y = pos >> 6, xc = pos & 63;
    f32x2 acc2[27];
#pragma unroll
    for (int p = 0; p < 27; ++p) acc2[p] = (f32x2){0.f, 0.f};
    const float* hp = h + (size_t)b * 2097152 + pos;
    for (int c4 = 0; c4 < 4; ++c4) {
        const int ci0 = c4 * 128;
        __syncthreads();
#pragma unroll
        for (int j = 0; j < 54; ++j) {
            wAll[t][j] = (j < 18) ? cls_w[j * 512 + ci0 + t]
                                  : loc_w[(j - 18) * 512 + ci0 + t];
        }
        __syncthreads();
#pragma unroll 4
        for (int cc = 0; cc < 128; ++cc) {
            const float hv = hp[(size_t)(ci0 + cc) * 4096];
            const f32x2 hv2 = (f32x2){hv, hv};
            const float* wr = &wAll[cc][0];
#pragma unroll
            for (int q = 0; q < 13; ++q) {
                const f32x4 w4 = *(const f32x4*)(wr + 4 * q);
                acc2[2 * q]     = __builtin_elementwise_fma((f32x2){w4[0], w4[1]}, hv2, acc2[2 * q]);
                acc2[2 * q + 1] = __builtin_elementwise_fma((f32x2){w4[2], w4[3]}, hv2, acc2[2 * q + 1]);
            }
            const f32x2 wtl = *(const f32x2*)(wr + 52);
            acc2[26] = __builtin_elementwise_fma(wtl, hv2, acc2[26]);
        }
    }
    float accC[18], accL[36];
#pragma unroll
    for (int o = 0; o < 18; ++o) accC[o] = acc2[o >> 1][o & 1];
#pragma unroll
    for (int l = 0; l < 36; ++l) accL[l] = acc2[9 + (l >> 1)][l & 1];
    const float fh = (float)(*img_h_p);
    const float fw = (float)(*img_w_p);
    {
        const size_t obase = (size_t)b * 73728 + (size_t)pos * 18;
#pragma unroll
        for (int o = 0; o < 18; ++o) {
            accC[o] += cls_b[o];
            out_cls[obase + o] = 1.f / (1.f + expf(-accC[o]));
        }
    }
    {
        const size_t lbase = (size_t)b * 147456 + (size_t)pos * 36;
#pragma unroll
        for (int o = 0; o < 36; ++o) {
            accL[o] += loc_b[o];
            out_loc[lbase + o] = accL[o];
        }
    }
    const float sy = (float)(y * 16), sx = (float)(xc * 16);
    const double RR[3] = {0.5, 1.0, 2.0};
    const double SS[3] = {8.0, 16.0, 32.0};
#pragma unroll
    for (int a = 0; a < 9; ++a) {
        const double r = RR[a / 3], s = SS[a % 3];
        const double hd = 16.0 * s * sqrt(r);
        const double wd = 16.0 * s * sqrt(1.0 / r);
        const float ab0 = (float)(-hd / 2.0), ab1 = (float)(-wd / 2.0);
        const float ab2 = (float)(hd / 2.0), ab3 = (float)(wd / 2.0);
        const float a0 = ab0 + sy, a1 = ab1 + sx, a2 = ab2 + sy, a3 = ab3 + sx;
        float hh = a2 - a0, ww = a3 - a1;
        float cy = a0 + 0.5f * hh, cx = a1 + 0.5f * ww;
        const float dy = accL[a * 4 + 0], dx = accL[a * 4 + 1];
        const float dh = accL[a * 4 + 2], dw = accL[a * 4 + 3];
        cy = cy + dy * hh;
        cx = cx + dx * ww;
        hh = hh * expf(dh);
        ww = ww * expf(dw);
        float y1 = cy - 0.5f * hh, x1 = cx - 0.5f * ww;
        float y2 = cy + 0.5f * hh, x2 = cx + 0.5f * ww;
        y1 = fminf(fmaxf(y1, 0.f), fh); x1 = fminf(fmaxf(x1, 0.f), fw);
        y2 = fminf(fmaxf(y2, 0.f), fh); x2 = fminf(fmaxf(x2, 0.f), fw);
        const bool valid = ((y2 - y1) >= 16.f) && ((x2 - x1) >= 16.f);
        const float sc = 1.f / (1.f + expf(-accC[a * 2 + 1]));
        const int n = pos * 9 + a;
        float* bp = boxes + ((size_t)b * 36864 + n) * 4;
        bp[0] = y1; bp[1] = x1; bp[2] = y2; bp[3] = x2;
        scores[(size_t)b * 36864 + n] = valid ? sc : -INFINITY;
    }
}

// ---------------- Stage C+D fused: top-6000 select (LDS sel) + 300-pick NMS ----------------
__device__ __forceinline__ unsigned fmap(float f) {
    unsigned bits = __float_as_uint(f);
    return ((int)bits < 0) ? ~bits : (bits | 0x80000000u);
}

__global__ __launch_bounds__(1024) void k_selnms(
        const float* __restrict__ scores, const float* __restrict__ boxes,
        float* __restrict__ rois, float* __restrict__ roi_idx) {
    __shared__ unsigned h2[16][256];          // 16 KB
    __shared__ unsigned hist[256];            // 1 KB
    __shared__ unsigned tieL[1024];           // 4 KB
    __shared__ unsigned selL[6000];           // 24 KB (was global)
    __shared__ unsigned long long warr[2][16];
    __shared__ float wbox[2][16][4];
    __shared__ unsigned sh_pref, sh_k, sh_cg, sh_ct;
    const int b = blockIdx.x;
    const int t = threadIdx.x;
    const int lane = t & 63;
    const int wid = t >> 6;
    const unsigned long long lmlt = (1ull << lane) - 1ull;
    const float* sp = scores + (size_t)b * 36864;

    // ======== Phase 1: exact top-6000 radix select (same semantics as r10) ========
    unsigned pref = 0;
    unsigned k = 6000;
    for (int p = 3; p >= 0; --p) {
        for (int z = t; z < 4096; z += 1024) ((unsigned*)h2)[z] = 0;
        __syncthreads();
        const int sh = p * 8;
        for (int i4 = t * 4; i4 < 36864; i4 += 4096) {
            const float4 v = *(const float4*)(sp + i4);
            const float vv[4] = {v.x, v.y, v.z, v.w};
#pragma unroll
            for (int e = 0; e < 4; ++e) {
                unsigned u = fmap(vv[e]);
                bool match = (p == 3) || ((u >> (sh + 8)) == (pref >> (sh + 8)));
                if (match) atomicAdd(&h2[wid][(u >> sh) & 255u], 1u);
            }
        }
        __syncthreads();
        if (t < 256) {
            unsigned s = 0;
#pragma unroll
            for (int j = 0; j < 16; ++j) s += h2[j][t];
            hist[t] = s;
        }
        __syncthreads();
        if (t == 0) {
            unsigned c = 0;
            int bsel = 0;
            for (int bin = 255; bin >= 0; --bin) {
                unsigned c2 = c + hist[bin];
                if (c2 >= k) { bsel = bin; k = k - c; break; }
                c = c2;
            }
            pref |= ((unsigned)bsel) << sh;
            sh_pref = pref; sh_k = k;
        }
        __syncthreads();
        pref = sh_pref; k = sh_k;
        __syncthreads();
    }
    if (t == 0) { sh_cg = 0; sh_ct = 0; }
    __syncthreads();
    const unsigned uthr = pref;
    for (int i4 = t * 4; i4 < 36864; i4 += 4096) {
        const float4 v = *(const float4*)(sp + i4);
        const float vv[4] = {v.x, v.y, v.z, v.w};
#pragma unroll
        for (int e = 0; e < 4; ++e) {
            const int i = i4 + e;
            unsigned u = fmap(vv[e]);
            const bool g = (u > uthr);
            const bool eq = (u == uthr);
            unsigned long long bg = __ballot(g);
            if (bg) {
                int lead = __ffsll((unsigned long long)bg) - 1;
                unsigned basev = 0;
                if (lane == lead) basev = atomicAdd(&sh_cg, (unsigned)__popcll(bg));
                basev = __shfl(basev, lead, 64);
                if (g) selL[basev + (unsigned)__popcll(bg & lmlt)] = (unsigned)i;
            }
            unsigned long long be = __ballot(eq);
            if (be) {
                int lead = __ffsll((unsigned long long)be) - 1;
                unsigned baset = 0;
                if (lane == lead) baset = atomicAdd(&sh_ct, (unsigned)__popcll(be));
                baset = __shfl(baset, lead, 64);
                if (eq) {
                    unsigned tp = baset + (unsigned)__popcll(be & lmlt);
                    if (tp < 1024) tieL[tp] = (unsigned)i;
                }
            }
        }
    }
    __syncthreads();
    const unsigned G = sh_cg;
    const unsigned T = sh_ct;
    const unsigned need = k;
    const unsigned Tc = T < 1024u ? T : 1024u;
    if ((unsigned)t >= Tc) tieL[t] = 0xFFFFFFFFu;
    __syncthreads();
    if (need > 0) {
        if (T > 1) {
            for (int kk = 2; kk <= 1024; kk <<= 1) {
                for (int j = kk >> 1; j > 0; j >>= 1) {
                    int ixj = t ^ j;
                    if (ixj > t) {
                        unsigned va = tieL[t], vb = tieL[ixj];
                        bool up = ((t & kk) == 0);
                        if (up ? (va > vb) : (va < vb)) { tieL[t] = vb; tieL[ixj] = va; }
                    }
                    __syncthreads();
                }
            }
        }
        if ((unsigned)t < need) selL[G + t] = tieL[t];
    }
    __syncthreads();

    // ======== Phase 2: sequential 300-pick NMS (same semantics as r10) ========
    const unsigned UNEG = 0x007FFFFFu;
    float bx[6][4];
    unsigned long long key[6];
#pragma unroll
    for (int j = 0; j < 6; ++j) {
        int s = t + j * 1024;
        if (s < 6000) {
            unsigned idx = selL[s];
            const float* bp = boxes + ((size_t)b * 36864 + idx) * 4;
            bx[j][0] = bp[0]; bx[j][1] = bp[1]; bx[j][2] = bp[2]; bx[j][3] = bp[3];
            unsigned u = fmap(sp[idx]);
            key[j] = ((unsigned long long)u << 32) | (unsigned)(~idx);
        } else {
            key[j] = 0ull;
            bx[j][0] = bx[j][1] = bx[j][2] = bx[j][3] = 0.f;
        }
    }
    float* orow = rois + (size_t)b * 300 * 4;
    for (int k2 = 0; k2 < 300; ++k2) {
        const int pb = k2 & 1;
        unsigned long long m = key[0];
        float b0 = bx[0][0], b1 = bx[0][1], b2 = bx[0][2], b3 = bx[0][3];
#pragma unroll
        for (int j = 1; j < 6; ++j) {
            if (key[j] > m) { m = key[j]; b0 = bx[j][0]; b1 = bx[j][1]; b2 = bx[j][2]; b3 = bx[j][3]; }
        }
        const unsigned long long lm = m;
#pragma unroll
        for (int d = 32; d > 0; d >>= 1) {
            unsigned long long o = __shfl_xor(m, d, 64);
            if (o > m) m = o;
        }
        unsigned long long own = __ballot(lm == m);
        if (lane == __ffsll(own) - 1) {
            warr[pb][wid] = m;
            wbox[pb][wid][0] = b0; wbox[pb][wid][1] = b1;
            wbox[pb][wid][2] = b2; wbox[pb][wid][3] = b3;
        }
        __syncthreads();
        unsigned long long wk = warr[pb][0];
        int wm = 0;
#pragma unroll
        for (int i = 1; i < 16; ++i) {
            unsigned long long v = warr[pb][i];
            if (v > wk) { wk = v; wm = i; }
        }
        const unsigned uhi = (unsigned)(wk >> 32);
        if (uhi > UNEG) {
            const float py1 = wbox[pb][wm][0], px1 = wbox[pb][wm][1];
            const float py2 = wbox[pb][wm][2], px2 = wbox[pb][wm][3];
            const float parea = (py2 - py1) * (px2 - px1);
            if (t == 0) {
                orow[k2 * 4 + 0] = py1; orow[k2 * 4 + 1] = px1;
                orow[k2 * 4 + 2] = py2; orow[k2 * 4 + 3] = px2;
                roi_idx[b * 300 + k2] = (float)b;
            }
#pragma unroll
            for (int j = 0; j < 6; ++j) {
                if ((unsigned)(key[j] >> 32) > UNEG) {
                    float yy1 = fmaxf(bx[j][0], py1);
                    float xx1 = fmaxf(bx[j][1], px1);
                    float yy2 = fminf(bx[j][2], py2);
                    float xx2 = fminf(bx[j][3], px2);
                    float inter = fmaxf(yy2 - yy1, 0.f) * fmaxf(xx2 - xx1, 0.f);
                    float area = (bx[j][2] - bx[j][0]) * (bx[j][3] - bx[j][1]);
                    float iou = inter / (area + parea - inter + 1e-9f);
                    if (iou > 0.7f)
                        key[j] = ((unsigned long long)UNEG << 32) | (key[j] & 0xFFFFFFFFull);
                }
            }
        } else {
            if (t == 0) {
                orow[k2 * 4 + 0] = 0.f; orow[k2 * 4 + 1] = 0.f;
                orow[k2 * 4 + 2] = 0.f; orow[k2 * 4 + 3] = 0.f;
                roi_idx[b * 300 + k2] = (float)b;
            }
        }
    }
}

extern "C" void kernel_launch(void* const* d_in, const int* in_sizes, int n_in,
                              void* d_out, int out_size, void* d_ws, size_t ws_size,
                              hipStream_t stream) {
    (void)in_sizes; (void)n_in; (void)out_size;
    const float* x      = (const float*)d_in[0];
    const float* conv_w = (const float*)d_in[1];
    const float* conv_b = (const float*)d_in[2];
    const float* loc_w  = (const float*)d_in[3];
    const float* loc_b  = (const float*)d_in[4];
    const float* cls_w  = (const float*)d_in[5];
    const float* cls_b  = (const float*)d_in[6];
    const int* img_h    = (const int*)d_in[7];
    const int* img_w    = (const int*)d_in[8];

    char* ws = (char*)d_ws;
    float*    h      = (float*)(ws + 0);
    float*    boxes  = (float*)(ws + 67108864);
    float*    scores = (float*)(ws + 71827456);
    float*    zp     = (float*)(ws + 73199104);
    float*    wT     = (float*)(ws + 73199360);

    float* out      = (float*)d_out;
    float* out_cls  = out;             // 589824
    float* out_loc  = out + 589824;    // 1179648
    float* rois     = out + 1769472;   // 9600
    float* ridx     = out + 1779072;   // 2400

    const bool big_ws = (ws_size >= 82636544ull);

    hipMemsetAsync(zp, 0, 256, stream);
    if (big_ws) {
        k_wtrans_t<<<dim3(72, 8), 256, 0, stream>>>(conv_w, wT);
        k_conv3x3_pk<<<dim3(16, 8, 8), 256, 0, stream>>>(x, wT, conv_b, zp, h);
    } else {
        k_conv3x3<<<dim3(16, 8, 8), 256, 0, stream>>>(x, conv_w, conv_b, zp, h);
    }
    k_head<<<dim3(256), 128, 0, stream>>>(h, cls_w, cls_b, loc_w, loc_b,
                                          img_h, img_w, out_cls, out_loc, boxes, scores);
    k_selnms<<<dim3(8), 1024, 0, stream>>>(scores, boxes, rois, ridx);
}